// Round 12
// baseline (227.466 us; speedup 1.0000x reference)
//
#include <hip/hip_runtime.h>

typedef __bf16 bf16x8 __attribute__((ext_vector_type(8)));
typedef float floatx4 __attribute__((ext_vector_type(4)));

#define MFMA(a, b, c) __builtin_amdgcn_mfma_f32_16x16x32_bf16(a, b, c, 0, 0, 0)

#define BNS 0.9999950000374997f  /* 1/sqrt(1+1e-5) */
#define LRELU(x) ((x) > 0.f ? (x) : 0.01f * (x))

__device__ inline float wave_sum(float v) {
#pragma unroll
  for (int s = 32; s > 0; s >>= 1) v += __shfl_xor(v, s, 64);
  return v;
}
__device__ inline float wave_max(float v) {
#pragma unroll
  for (int s = 32; s > 0; s >>= 1) v = fmaxf(v, __shfl_xor(v, s, 64));
  return v;
}

// ---------------------------------------------------------------------------
// k_prep: weight swizzles (r9 version).
// ---------------------------------------------------------------------------
__global__ __launch_bounds__(256) void k_prep(const float* __restrict__ pre_w1,
                                              const float* __restrict__ ps_w1,
                                              const float* __restrict__ pre_w2,
                                              const float* __restrict__ ps_w2,
                                              const float* __restrict__ dw1,
                                              const float* __restrict__ dw2,
                                              const float* __restrict__ mwq,
                                              const float* __restrict__ mwk,
                                              __bf16* __restrict__ w1b,
                                              __bf16* __restrict__ w2b,
                                              __bf16* __restrict__ d1i,
                                              __bf16* __restrict__ d2i,
                                              __bf16* __restrict__ qki) {
  const int tt = blockIdx.x * 256 + threadIdx.x;
  bf16x8 v;
  if (tt < 24576) {
    const int buf = tt / 12288;
    const int r = tt % 12288;
    const int set = r >> 12;
    const int q = r & 4095;
    const int ln = q & 63, qd = ln >> 4, cc = ln & 15;
    const int wv = (q >> 6) & 3;
    if (buf == 0) {
      const int kt = (q >> 8) & 3, qtr = (q >> 10) & 3;
      const float* src = (set == 0) ? pre_w1 : ps_w1 + (size_t)(set - 1) * 32768;
      const float* p = src + (size_t)(kt * 32 + qd * 8) * 256 + qtr * 64 + wv * 16 + cc;
#pragma unroll
      for (int jj = 0; jj < 8; jj++) v[jj] = (__bf16)p[jj * 256];
      *(bf16x8*)&w1b[(size_t)set * 32768 + q * 8] = v;
    } else {
      const int kt = (q >> 8) & 1, nt = (q >> 9) & 1, qtr = (q >> 10) & 3;
      const float* src = (set == 0) ? pre_w2 : ps_w2 + (size_t)(set - 1) * 32768;
      const float* p = src + (size_t)(qtr * 64 + kt * 32 + qd * 8) * 128 + wv * 32 + nt * 16 + cc;
#pragma unroll
      for (int jj = 0; jj < 8; jj++) v[jj] = (__bf16)p[jj * 128];
      *(bf16x8*)&w2b[(size_t)set * 32768 + q * 8] = v;
    }
  } else if (tt < 40960) {
    const int u = tt - 24576;
    const int gen = u >> 13, r = u & 8191;
    const int nt = r >> 9, kt = (r >> 6) & 7, ln = r & 63;
    const int qd = ln >> 4, cc = ln & 15;
    const float* src = dw1 + (size_t)gen * 65536 + (size_t)(kt * 32 + qd * 8) * 256 + nt * 16 + cc;
#pragma unroll
    for (int jj = 0; jj < 8; jj++) v[jj] = (__bf16)src[jj * 256];
    *(bf16x8*)&d1i[((size_t)gen * 65536) + (size_t)r * 8] = v;
  } else if (tt < 49152) {
    const int u = tt - 40960;
    const int gen = u >> 12, r = u & 4095;
    const int nt = r >> 9, kt = (r >> 6) & 7, ln = r & 63;
    const int qd = ln >> 4, cc = ln & 15;
    const float* src = dw2 + (size_t)gen * 32768 + (size_t)(kt * 32 + qd * 8) * 128 + nt * 16 + cc;
#pragma unroll
    for (int jj = 0; jj < 8; jj++) v[jj] = (__bf16)src[jj * 128];
    *(bf16x8*)&d2i[((size_t)gen * 32768) + (size_t)r * 8] = v;
  } else if (tt < 57344) {
    const int u = tt - 49152;
    const int gen = u >> 12, r = u & 4095, qk = r >> 11, r2 = r & 2047;
    const int cb = r2 >> 7, o = r2 & 127;
    const float* src = (qk ? mwk : mwq) + (size_t)gen * 16384 + (size_t)(cb * 8) * 128 + o;
#pragma unroll
    for (int jj = 0; jj < 8; jj++) v[jj] = (__bf16)src[jj * 128];
    *(bf16x8*)&qki[(size_t)((((gen * 2 + qk) * 16 + cb) * 128 + o)) * 8] = v;
  }
}

// ---------------------------------------------------------------------------
// k_psim: r9 structure (r4 + qtr-0 prefetch) + phase-E compression:
//  ep_sum hoisted before K-loop; single-pass top-k; closed-form rsum.
//  Phase E barrier count: 5 -> 1.
// ---------------------------------------------------------------------------
__global__ void __launch_bounds__(256, 3)
k_psim(const float* __restrict__ vp, const float* __restrict__ ep_in,
       float* __restrict__ ep_out,
       const __bf16* __restrict__ w1b, const __bf16* __restrict__ w2b,
       const float* __restrict__ w3, const float* __restrict__ b3,
       int kval, float* __restrict__ outp) {
  __shared__ __bf16 simf[16384];
  __shared__ __bf16 hbf[8192];
  __shared__ float ep_row[128];
  __shared__ float e_row[128];
  __shared__ float w3s[128];
  __shared__ float red[256];
  __shared__ float red2[4];
  __shared__ float eps2[4];

  const int tid = threadIdx.x;
  const int b = blockIdx.x >> 7, i = blockIdx.x & 127;
  const float* vpb = vp + ((size_t)b << 14);
  const float* vpi = vpb + (i << 7);
  const size_t rowoff = ((size_t)blockIdx.x) << 7;

  const int wv = tid >> 6;
  const int ln = tid & 63;
  const int qd = ln >> 4;
  const int cc = ln & 15;

  {
    const int j = tid >> 1;
    const int c0 = (tid & 1) << 6;
    const int m = j >> 4, ccr = j & 15;
    const float* vpj = vpb + (j << 7) + c0;
    const float* vpx = vpi + c0;
#pragma unroll
    for (int c = 0; c < 64; c += 8) {
      const int gc = c0 + c;
      const int kt = gc >> 5, qdw = (gc >> 3) & 3;
      float4 a0 = *(const float4*)(vpj + c);
      float4 a1 = *(const float4*)(vpj + c + 4);
      float4 b0 = *(const float4*)(vpx + c);
      float4 b1 = *(const float4*)(vpx + c + 4);
      bf16x8 t;
      float d;
      d = a0.x - b0.x; t[0] = (__bf16)(d * d);
      d = a0.y - b0.y; t[1] = (__bf16)(d * d);
      d = a0.z - b0.z; t[2] = (__bf16)(d * d);
      d = a0.w - b0.w; t[3] = (__bf16)(d * d);
      d = a1.x - b1.x; t[4] = (__bf16)(d * d);
      d = a1.y - b1.y; t[5] = (__bf16)(d * d);
      d = a1.z - b1.z; t[6] = (__bf16)(d * d);
      d = a1.w - b1.w; t[7] = (__bf16)(d * d);
      *(bf16x8*)&simf[(((kt << 3) + m) << 6 | (qdw << 4 | ccr)) << 3] = t;
    }
    if (tid < 128) {
      ep_row[tid] = (tid == i) ? 0.f : ep_in[rowoff + tid];
      w3s[tid] = w3[tid];
    }
  }

  bf16x8 bw[4], bw2[2][2];
#pragma unroll
  for (int kt = 0; kt < 4; kt++)
    bw[kt] = *(const bf16x8*)&w1b[(((0 * 4 + kt) * 4 + wv) * 64 + ln) * 8];
#pragma unroll
  for (int nt = 0; nt < 2; nt++)
#pragma unroll
    for (int kt = 0; kt < 2; kt++)
      bw2[nt][kt] = *(const bf16x8*)&w2b[((((0 * 2 + nt) * 2 + kt) * 4 + wv) * 64 + ln) * 8];

  __syncthreads();

  // ep_sum partials hoisted here (read only after the K-loop's barriers)
  {
    float v = (tid < 128) ? ep_row[tid] : 0.f;
    float w = wave_sum(v);
    if (ln == 0) eps2[wv] = w;
  }

  floatx4 acc2[8][2];
#pragma unroll
  for (int m = 0; m < 8; m++) {
    acc2[m][0] = (floatx4){0.f, 0.f, 0.f, 0.f};
    acc2[m][1] = (floatx4){0.f, 0.f, 0.f, 0.f};
  }

  const int h1h = wv >> 1;
  const int h1qd = ((wv & 1) << 1) | (cc >> 3);
  const int h1jj = cc & 7;

#pragma unroll
  for (int qtr = 0; qtr < 4; qtr++) {
    bf16x8 bwn[4], bw2n[2][2];
    if (qtr < 3) {
#pragma unroll
      for (int kt = 0; kt < 4; kt++)
        bwn[kt] = *(const bf16x8*)&w1b[((((qtr + 1) * 4 + kt) * 4 + wv) * 64 + ln) * 8];
#pragma unroll
      for (int nt = 0; nt < 2; nt++)
#pragma unroll
        for (int kt = 0; kt < 2; kt++)
          bw2n[nt][kt] = *(const bf16x8*)&w2b[(((((qtr + 1) * 2 + nt) * 2 + kt) * 4 + wv) * 64 + ln) * 8];
    }

#pragma unroll
    for (int m2 = 0; m2 < 8; m2 += 2) {
      bf16x8 af0[4], af1[4];
#pragma unroll
      for (int kt = 0; kt < 4; kt++) {
        af0[kt] = *(const bf16x8*)&simf[(((kt << 3) + m2) << 6 | ln) << 3];
        af1[kt] = *(const bf16x8*)&simf[(((kt << 3) + m2 + 1) << 6 | ln) << 3];
      }
      floatx4 x0 = (floatx4){0.f, 0.f, 0.f, 0.f};
      floatx4 x1 = (floatx4){0.f, 0.f, 0.f, 0.f};
#pragma unroll
      for (int kt = 0; kt < 4; kt++) {
        x0 = MFMA(af0[kt], bw[kt], x0);
        x1 = MFMA(af1[kt], bw[kt], x1);
      }
#pragma unroll
      for (int r = 0; r < 4; r++) {
        float v0 = x0[r] * BNS;
        float v1 = x1[r] * BNS;
        hbf[(((h1h * 8 + m2) * 64) + h1qd * 16 + qd * 4 + r) * 8 + h1jj] = (__bf16)LRELU(v0);
        hbf[(((h1h * 8 + m2 + 1) * 64) + h1qd * 16 + qd * 4 + r) * 8 + h1jj] = (__bf16)LRELU(v1);
      }
    }
    __syncthreads();

#pragma unroll
    for (int m = 0; m < 8; m++) {
      bf16x8 a0 = *(const bf16x8*)&hbf[((m << 6) | ln) << 3];
      bf16x8 a1 = *(const bf16x8*)&hbf[(((8 + m) << 6) | ln) << 3];
      acc2[m][0] = MFMA(a0, bw2[0][0], acc2[m][0]);
      acc2[m][1] = MFMA(a0, bw2[1][0], acc2[m][1]);
      acc2[m][0] = MFMA(a1, bw2[0][1], acc2[m][0]);
      acc2[m][1] = MFMA(a1, bw2[1][1], acc2[m][1]);
    }
    __syncthreads();

    if (qtr < 3) {
#pragma unroll
      for (int kt = 0; kt < 4; kt++) bw[kt] = bwn[kt];
#pragma unroll
      for (int nt = 0; nt < 2; nt++)
#pragma unroll
        for (int kt = 0; kt < 2; kt++) bw2[nt][kt] = bw2n[nt][kt];
    }
  }

  {
    const int seg = wv;
#pragma unroll
    for (int m = 0; m < 8; m++)
#pragma unroll
      for (int nt = 0; nt < 2; nt++) {
        const int q2 = (nt << 1) | (cc >> 3);
#pragma unroll
        for (int r = 0; r < 4; r++) {
          float v = acc2[m][nt][r] * BNS;
          simf[(((seg * 8 + m) * 64) + q2 * 16 + qd * 4 + r) * 8 + (cc & 7)] = (__bf16)LRELU(v);
        }
      }
  }
  __syncthreads();

  {
    const int j = tid & 127, hh = tid >> 7;
    const int m = j >> 4, R = j & 15;
    float s = 0.f;
#pragma unroll
    for (int sg = 0; sg < 2; sg++) {
      const int seg = hh * 2 + sg;
#pragma unroll
      for (int q3 = 0; q3 < 4; q3++) {
        bf16x8 f = *(const bf16x8*)&simf[(((seg * 8 + m) * 64) + q3 * 16 + R) * 8];
        const float* wp = &w3s[seg * 32 + q3 * 8];
#pragma unroll
        for (int jj = 0; jj < 8; jj++) s += (float)f[jj] * wp[jj];
      }
    }
    red[tid] = s;
  }
  __syncthreads();
  if (tid < 128) {
    float s = red[tid] + red[tid + 128] + b3[0];
    float sg = 1.f / (1.f + expf(-s));
    e_row[tid] = sg * ep_row[tid];
  }
  __syncthreads();

  // ---- Phase E (compressed): single-pass top-k, one reduction, closed rsum ----
  float em = 0.f;
  if (tid < 128) {
    float v = e_row[tid];
    if (kval > 0) {  // stable rank-count == jax.lax.top_k tie-break
      int cnt = 0;
#pragma unroll 8
      for (int jj = 0; jj < 128; jj++) {
        float u = e_row[jj];
        cnt += (u > v || (u == v && jj < tid)) ? 1 : 0;
      }
      em = (cnt < kval) ? v : 0.f;
    } else {
      em = v;
    }
  }
  {
    float w = wave_sum((tid < 128) ? em : 0.f);
    if (ln == 0) red2[wv] = w;
  }
  __syncthreads();
  const float l1 = red2[0] + red2[1];
  const float ep_sum = eps2[0] + eps2[1];
  const float scale = ep_sum / fmaxf(l1, 1e-12f);
  // rsum = sum_j(em*scale + eye + 1e-6) = scale*l1 + 1 + 128e-6 (closed form)
  const float rsum = scale * l1 + 1.0f + 1.28e-4f;

  if (tid < 128) {
    float o = (em * scale + ((tid == i) ? 1.f : 0.f) + 1e-6f) / rsum;
    ep_out[rowoff + tid] = o;
    if (outp) outp[rowoff + tid] = o;
  }
}

// ---------------------------------------------------------------------------
// k_qk: interleaved bf16x8 weights -> 16 coalesced 16B loads per thread.
// ---------------------------------------------------------------------------
__global__ __launch_bounds__(256) void k_qk(const float* __restrict__ vp,
                                            const __bf16* __restrict__ qkw,
                                            float* __restrict__ qo,
                                            float* __restrict__ ko) {
  __shared__ float vr[128];
  const int t = threadIdx.x;
  const size_t rowoff = ((size_t)blockIdx.x) << 7;
  if (t < 128) vr[t] = vp[rowoff + t];
  __syncthreads();
  const int o = t & 127;
  const __bf16* base = qkw + ((t >> 7) ? 16384 : 0);
  const float4* vr4 = (const float4*)vr;
  float a = 0.f;
#pragma unroll
  for (int cb = 0; cb < 16; cb++) {
    bf16x8 w8 = *(const bf16x8*)&base[(cb * 128 + o) * 8];
    float4 v0 = vr4[2 * cb], v1 = vr4[2 * cb + 1];
    a += v0.x * (float)w8[0] + v0.y * (float)w8[1] + v0.z * (float)w8[2] + v0.w * (float)w8[3] +
         v1.x * (float)w8[4] + v1.y * (float)w8[5] + v1.z * (float)w8[6] + v1.w * (float)w8[7];
  }
  float* dst = (t < 128) ? qo : ko;
  dst[rowoff + o] = a;
}

// ---------------------------------------------------------------------------
// k_attn_agg: 2-row attn/edge/aggr (grid 512); writes agg to global. (r9)
// ---------------------------------------------------------------------------
__global__ __launch_bounds__(256) void k_attn_agg(const float* __restrict__ qv,
                                                  const float* __restrict__ kv,
                                                  const float* __restrict__ ep,
                                                  const float* __restrict__ vp_in,
                                                  float* __restrict__ agg) {
  __shared__ float qi[256];
  __shared__ float sbuf[1024];
  __shared__ float er[256];
  __shared__ float pbuf[2048];
  __shared__ float red2[4];

  const int tid = threadIdx.x;
  const int wv = tid >> 6, ln = tid & 63;
  const int b = blockIdx.x >> 6;
  const int r0 = (blockIdx.x & 63) * 2;
  const size_t rowoff0 = ((size_t)(b * 128 + r0)) << 7;
  const float* vpbb = vp_in + ((size_t)b << 14);

  qi[tid] = qv[rowoff0 + tid];
  __syncthreads();

  {
    const int j = tid & 127, hh = tid >> 7;
    const float* krow = kv + (((size_t)(b * 128 + j)) << 7);
    const int h0 = hh * 2, h1 = hh * 2 + 1;
    float s00 = 0.f, s01 = 0.f, s10 = 0.f, s11 = 0.f;
#pragma unroll
    for (int d = 0; d < 32; d += 4) {
      float4 k0 = *(const float4*)(krow + h0 * 32 + d);
      float4 k1 = *(const float4*)(krow + h1 * 32 + d);
      s00 += qi[h0 * 32 + d] * k0.x + qi[h0 * 32 + d + 1] * k0.y +
             qi[h0 * 32 + d + 2] * k0.z + qi[h0 * 32 + d + 3] * k0.w;
      s01 += qi[h1 * 32 + d] * k1.x + qi[h1 * 32 + d + 1] * k1.y +
             qi[h1 * 32 + d + 2] * k1.z + qi[h1 * 32 + d + 3] * k1.w;
      s10 += qi[128 + h0 * 32 + d] * k0.x + qi[128 + h0 * 32 + d + 1] * k0.y +
             qi[128 + h0 * 32 + d + 2] * k0.z + qi[128 + h0 * 32 + d + 3] * k0.w;
      s11 += qi[128 + h1 * 32 + d] * k1.x + qi[128 + h1 * 32 + d + 1] * k1.y +
             qi[128 + h1 * 32 + d + 2] * k1.z + qi[128 + h1 * 32 + d + 3] * k1.w;
    }
    const float sc = 0.17677669529663687f;
    sbuf[(0 * 4 + h0) * 128 + j] = s00 * sc;
    sbuf[(0 * 4 + h1) * 128 + j] = s01 * sc;
    sbuf[(1 * 4 + h0) * 128 + j] = s10 * sc;
    sbuf[(1 * 4 + h1) * 128 + j] = s11 * sc;
  }
  __syncthreads();

  {
    const int g = wv;
#pragma unroll
    for (int row = 0; row < 2; row++) {
      float a = sbuf[(row * 4 + g) * 128 + ln];
      float bb = sbuf[(row * 4 + g) * 128 + 64 + ln];
      float mx = wave_max(fmaxf(a, bb));
      float e0 = expf(a - mx), e1 = expf(bb - mx);
      float Z = wave_sum(e0 + e1);
      sbuf[(row * 4 + g) * 128 + ln] = e0 / Z;
      sbuf[(row * 4 + g) * 128 + 64 + ln] = e1 / Z;
    }
  }
  __syncthreads();

  {
    const int row = tid >> 7, j = tid & 127;
    float attn = 0.25f * (sbuf[(row * 4) * 128 + j] + sbuf[(row * 4 + 1) * 128 + j] +
                          sbuf[(row * 4 + 2) * 128 + j] + sbuf[(row * 4 + 3) * 128 + j]);
    float eraw = (j == r0 + row) ? 0.f : ep[rowoff0 + tid] * attn;
    float w = wave_sum(eraw);
    if (ln == 0) red2[wv] = w;
    __syncthreads();
    float l1row = red2[row * 2] + red2[row * 2 + 1];
    er[tid] = eraw / fmaxf(l1row, 1e-12f);
  }
  __syncthreads();

  {
    const int cg = tid & 31, jg = tid >> 5;
    float4 a0 = {0.f, 0.f, 0.f, 0.f}, a1 = {0.f, 0.f, 0.f, 0.f};
#pragma unroll
    for (int jj = 0; jj < 16; jj++) {
      const int j = jg * 16 + jj;
      float4 v = *(const float4*)(vpbb + (j << 7) + (cg << 2));
      float e0 = er[j], e1 = er[128 + j];
      a0.x += e0 * v.x; a0.y += e0 * v.y; a0.z += e0 * v.z; a0.w += e0 * v.w;
      a1.x += e1 * v.x; a1.y += e1 * v.y; a1.z += e1 * v.z; a1.w += e1 * v.w;
    }
    *(float4*)&pbuf[(jg * 32 + cg) * 4] = a0;
    *(float4*)&pbuf[1024 + (jg * 32 + cg) * 4] = a1;
  }
  __syncthreads();
  {
    const int row = tid >> 7, c = tid & 127;
    float s = 0.f;
#pragma unroll
    for (int jg = 0; jg < 8; jg++) s += pbuf[(row << 10) + jg * 128 + c];
    agg[rowoff0 + tid] = s;
  }
}

// ---------------------------------------------------------------------------
// k_mlp: batched d2p MLP over all 1024 rows via MFMA (grid 64, unchanged).
// ---------------------------------------------------------------------------
__global__ __launch_bounds__(256) void k_mlp(const float* __restrict__ vp_in,
                                             const float* __restrict__ agg,
                                             const __bf16* __restrict__ d1,
                                             const __bf16* __restrict__ d2,
                                             float* __restrict__ vp_out) {
  __shared__ __bf16 hls[4096];
  const int tid = threadIdx.x;
  const int wv = tid >> 6, ln = tid & 63, qd = ln >> 4, cc = ln & 15;
  const int row = (blockIdx.x << 4) + cc;

  bf16x8 af[8];
#pragma unroll
  for (int kt = 0; kt < 4; kt++) {
    const float* p = vp_in + (size_t)row * 128 + kt * 32 + qd * 8;
    float4 v0 = *(const float4*)p, v1 = *(const float4*)(p + 4);
    bf16x8 t;
    t[0] = (__bf16)v0.x; t[1] = (__bf16)v0.y; t[2] = (__bf16)v0.z; t[3] = (__bf16)v0.w;
    t[4] = (__bf16)v1.x; t[5] = (__bf16)v1.y; t[6] = (__bf16)v1.z; t[7] = (__bf16)v1.w;
    af[kt] = t;
  }
#pragma unroll
  for (int kt = 0; kt < 4; kt++) {
    const float* p = agg + (size_t)row * 128 + kt * 32 + qd * 8;
    float4 v0 = *(const float4*)p, v1 = *(const float4*)(p + 4);
    bf16x8 t;
    t[0] = (__bf16)v0.x; t[1] = (__bf16)v0.y; t[2] = (__bf16)v0.z; t[3] = (__bf16)v0.w;
    t[4] = (__bf16)v1.x; t[5] = (__bf16)v1.y; t[6] = (__bf16)v1.z; t[7] = (__bf16)v1.w;
    af[4 + kt] = t;
  }

#pragma unroll
  for (int nt = 0; nt < 4; nt++) {
    const int ntg = wv * 4 + nt;
    floatx4 acc = (floatx4){0.f, 0.f, 0.f, 0.f};
#pragma unroll
    for (int kt = 0; kt < 8; kt++) {
      bf16x8 bw = *(const bf16x8*)&d1[((size_t)(ntg * 8 + kt) * 64 + ln) * 8];
      acc = MFMA(af[kt], bw, acc);
    }
    const int col = ntg * 16 + cc;
    const int kt2 = col >> 5, qd2 = (col >> 3) & 3, jjs = col & 7;
#pragma unroll
    for (int r = 0; r < 4; r++) {
      float h = acc[r] * BNS;
      const int m = qd * 4 + r;
      hls[((kt2 * 64) + qd2 * 16 + m) * 8 + jjs] = (__bf16)LRELU(h);
    }
  }
  __syncthreads();

  bf16x8 a2[8];
#pragma unroll
  for (int kt2 = 0; kt2 < 8; kt2++)
    a2[kt2] = *(const bf16x8*)&hls[(kt2 * 64 + ln) * 8];
#pragma unroll
  for (int nt = 0; nt < 2; nt++) {
    const int ntg = wv * 2 + nt;
    floatx4 o = (floatx4){0.f, 0.f, 0.f, 0.f};
#pragma unroll
    for (int kt2 = 0; kt2 < 8; kt2++) {
      bf16x8 bw = *(const bf16x8*)&d2[((size_t)(ntg * 8 + kt2) * 64 + ln) * 8];
      o = MFMA(a2[kt2], bw, o);
    }
    const int col = ntg * 16 + cc;
#pragma unroll
    for (int r = 0; r < 4; r++) {
      float v = o[r] * BNS;
      const int m = qd * 4 + r;
      vp_out[(size_t)((blockIdx.x << 4) + m) * 128 + col] = LRELU(v);
    }
  }
}

// ---------------------------------------------------------------------------
extern "C" void kernel_launch(void* const* d_in, const int* in_sizes, int n_in,
                              void* d_out, int out_size, void* d_ws, size_t ws_size,
                              hipStream_t stream) {
  const float* vp0    = (const float*)d_in[0];
  const float* ep0    = (const float*)d_in[1];
  const float* pre_w1 = (const float*)d_in[2];
  const float* pre_w2 = (const float*)d_in[3];
  const float* pre_w3 = (const float*)d_in[4];
  const float* pre_b3 = (const float*)d_in[5];
  const float* ps_w1  = (const float*)d_in[6];
  const float* ps_w2  = (const float*)d_in[7];
  const float* ps_w3  = (const float*)d_in[8];
  const float* ps_b3  = (const float*)d_in[9];
  const float* dw1    = (const float*)d_in[10];
  const float* dw2    = (const float*)d_in[11];
  const float* mwq    = (const float*)d_in[12];
  const float* mwk    = (const float*)d_in[13];

  char* ws = (char*)d_ws;
  float* ep   = (float*)(ws);                      // 512 KB
  float* vpb  = (float*)(ws + (512ull << 10));     // 512 KB
  float* vpa  = (float*)(ws + (1024ull << 10));    // 512 KB
  float* qf   = (float*)(ws + (1536ull << 10));    // 512 KB
  float* kf   = (float*)(ws + (2048ull << 10));    // 512 KB
  __bf16* w1b = (__bf16*)(ws + (2560ull << 10));            // 192 KB
  __bf16* w2b = (__bf16*)(ws + (2560ull << 10) + 196608);   // 192 KB
  __bf16* d1i = (__bf16*)(ws + (2560ull << 10) + 393216);   // 256 KB
  __bf16* d2i = (__bf16*)(ws + (2560ull << 10) + 655360);   // 128 KB
  __bf16* qki = (__bf16*)(ws + (2560ull << 10) + 786432);   // 128 KB
  float* agg  = (float*)(ws + (2560ull << 10) + 917504);    // 512 KB
  float* outp = (float*)d_out;

  k_prep<<<224, 256, 0, stream>>>(pre_w1, ps_w1, pre_w2, ps_w2, dw1, dw2, mwq, mwk,
                                  w1b, w2b, d1i, d2i, qki);

  // pre-psim (no top-k)
  k_psim<<<1024, 256, 0, stream>>>(vp0, ep0, ep, w1b, w2b, pre_w3, pre_b3, 0, nullptr);

  // generation 0 (kval = 115)
  k_qk<<<1024, 256, 0, stream>>>(vp0, qki, qf, kf);
  k_attn_agg<<<512, 256, 0, stream>>>(qf, kf, ep, vp0, agg);
  k_mlp<<<64, 256, 0, stream>>>(vp0, agg, d1i, d2i, vpb);
  k_psim<<<1024, 256, 0, stream>>>(vpb, ep, ep, w1b + 32768, w2b + 32768,
                                   ps_w3, ps_b3, 115, nullptr);

  // generation 1 (kval = 102)
  k_qk<<<1024, 256, 0, stream>>>(vpb, qki + 32768, qf, kf);
  k_attn_agg<<<512, 256, 0, stream>>>(qf, kf, ep, vpb, agg);
  k_mlp<<<64, 256, 0, stream>>>(vpb, agg, d1i + 65536, d2i + 32768, vpa);
  k_psim<<<1024, 256, 0, stream>>>(vpa, ep, ep, w1b + 65536, w2b + 65536,
                                   ps_w3 + 128, ps_b3 + 1, 102, outp);
}

// Round 13
// 222.272 us; speedup vs baseline: 1.0234x; 1.0234x over previous
//
#include <hip/hip_runtime.h>

typedef __bf16 bf16x8 __attribute__((ext_vector_type(8)));
typedef float floatx4 __attribute__((ext_vector_type(4)));

#define MFMA(a, b, c) __builtin_amdgcn_mfma_f32_16x16x32_bf16(a, b, c, 0, 0, 0)

#define BNS 0.9999950000374997f  /* 1/sqrt(1+1e-5) */
#define LRELU(x) ((x) > 0.f ? (x) : 0.01f * (x))

__device__ inline float wave_sum(float v) {
#pragma unroll
  for (int s = 32; s > 0; s >>= 1) v += __shfl_xor(v, s, 64);
  return v;
}
__device__ inline float wave_max(float v) {
#pragma unroll
  for (int s = 32; s > 0; s >>= 1) v = fmaxf(v, __shfl_xor(v, s, 64));
  return v;
}

// ---------------------------------------------------------------------------
// k_prep: weight swizzles (blocks 0-223, r9 layouts) + gen-0 q/k projection
// (blocks 224-1247: one (b,i) row each; reads raw fp32 mwq/mwk with inline
// bf16 conversion -> same rounding as the swizzled-qki path).
// ---------------------------------------------------------------------------
__global__ __launch_bounds__(256) void k_prep(const float* __restrict__ pre_w1,
                                              const float* __restrict__ ps_w1,
                                              const float* __restrict__ pre_w2,
                                              const float* __restrict__ ps_w2,
                                              const float* __restrict__ dw1,
                                              const float* __restrict__ dw2,
                                              const float* __restrict__ mwq,
                                              const float* __restrict__ mwk,
                                              const float* __restrict__ vp0,
                                              __bf16* __restrict__ w1b,
                                              __bf16* __restrict__ w2b,
                                              __bf16* __restrict__ d1i,
                                              __bf16* __restrict__ d2i,
                                              __bf16* __restrict__ qki,
                                              float* __restrict__ qo,
                                              float* __restrict__ ko) {
  if (blockIdx.x >= 224) {
    // ---- gen-0 q/k projection: one row per block ----
    __shared__ float vr[128];
    const int t = threadIdx.x;
    const size_t rowoff = ((size_t)(blockIdx.x - 224)) << 7;
    if (t < 128) vr[t] = vp0[rowoff + t];
    __syncthreads();
    const int o = t & 127;
    const float* w = (t < 128) ? mwq : mwk;   // gen 0
    const float4* vr4 = (const float4*)vr;
    float a = 0.f;
#pragma unroll
    for (int cb = 0; cb < 16; cb++) {
      float4 v0 = vr4[2 * cb], v1 = vr4[2 * cb + 1];
      const float* wp = w + (size_t)(cb * 8) * 128 + o;
      a += v0.x * (float)(__bf16)wp[0 * 128] + v0.y * (float)(__bf16)wp[1 * 128] +
           v0.z * (float)(__bf16)wp[2 * 128] + v0.w * (float)(__bf16)wp[3 * 128] +
           v1.x * (float)(__bf16)wp[4 * 128] + v1.y * (float)(__bf16)wp[5 * 128] +
           v1.z * (float)(__bf16)wp[6 * 128] + v1.w * (float)(__bf16)wp[7 * 128];
    }
    float* dst = (t < 128) ? qo : ko;
    dst[rowoff + o] = a;
    return;
  }

  const int tt = blockIdx.x * 256 + threadIdx.x;
  bf16x8 v;
  if (tt < 24576) {
    const int buf = tt / 12288;
    const int r = tt % 12288;
    const int set = r >> 12;
    const int q = r & 4095;
    const int ln = q & 63, qd = ln >> 4, cc = ln & 15;
    const int wv = (q >> 6) & 3;
    if (buf == 0) {
      const int kt = (q >> 8) & 3, qtr = (q >> 10) & 3;
      const float* src = (set == 0) ? pre_w1 : ps_w1 + (size_t)(set - 1) * 32768;
      const float* p = src + (size_t)(kt * 32 + qd * 8) * 256 + qtr * 64 + wv * 16 + cc;
#pragma unroll
      for (int jj = 0; jj < 8; jj++) v[jj] = (__bf16)p[jj * 256];
      *(bf16x8*)&w1b[(size_t)set * 32768 + q * 8] = v;
    } else {
      const int kt = (q >> 8) & 1, nt = (q >> 9) & 1, qtr = (q >> 10) & 3;
      const float* src = (set == 0) ? pre_w2 : ps_w2 + (size_t)(set - 1) * 32768;
      const float* p = src + (size_t)(qtr * 64 + kt * 32 + qd * 8) * 128 + wv * 32 + nt * 16 + cc;
#pragma unroll
      for (int jj = 0; jj < 8; jj++) v[jj] = (__bf16)p[jj * 128];
      *(bf16x8*)&w2b[(size_t)set * 32768 + q * 8] = v;
    }
  } else if (tt < 40960) {
    const int u = tt - 24576;
    const int gen = u >> 13, r = u & 8191;
    const int nt = r >> 9, kt = (r >> 6) & 7, ln = r & 63;
    const int qd = ln >> 4, cc = ln & 15;
    const float* src = dw1 + (size_t)gen * 65536 + (size_t)(kt * 32 + qd * 8) * 256 + nt * 16 + cc;
#pragma unroll
    for (int jj = 0; jj < 8; jj++) v[jj] = (__bf16)src[jj * 256];
    *(bf16x8*)&d1i[((size_t)gen * 65536) + (size_t)r * 8] = v;
  } else if (tt < 49152) {
    const int u = tt - 40960;
    const int gen = u >> 12, r = u & 4095;
    const int nt = r >> 9, kt = (r >> 6) & 7, ln = r & 63;
    const int qd = ln >> 4, cc = ln & 15;
    const float* src = dw2 + (size_t)gen * 32768 + (size_t)(kt * 32 + qd * 8) * 128 + nt * 16 + cc;
#pragma unroll
    for (int jj = 0; jj < 8; jj++) v[jj] = (__bf16)src[jj * 128];
    *(bf16x8*)&d2i[((size_t)gen * 32768) + (size_t)r * 8] = v;
  } else if (tt < 57344) {
    const int u = tt - 49152;
    const int gen = u >> 12, r = u & 4095, qk = r >> 11, r2 = r & 2047;
    const int cb = r2 >> 7, o = r2 & 127;
    const float* src = (qk ? mwk : mwq) + (size_t)gen * 16384 + (size_t)(cb * 8) * 128 + o;
#pragma unroll
    for (int jj = 0; jj < 8; jj++) v[jj] = (__bf16)src[jj * 128];
    *(bf16x8*)&qki[(size_t)((((gen * 2 + qk) * 16 + cb) * 128 + o)) * 8] = v;
  }
}

// ---------------------------------------------------------------------------
// k_psim: BYTE-EXACT r9 version (r4 + qtr-0 prefetch, 3 blocks/CU).
// ---------------------------------------------------------------------------
__global__ void __launch_bounds__(256, 3)
k_psim(const float* __restrict__ vp, const float* __restrict__ ep_in,
       float* __restrict__ ep_out,
       const __bf16* __restrict__ w1b, const __bf16* __restrict__ w2b,
       const float* __restrict__ w3, const float* __restrict__ b3,
       int kval, float* __restrict__ outp) {
  __shared__ __bf16 simf[16384];
  __shared__ __bf16 hbf[8192];
  __shared__ float ep_row[128];
  __shared__ float e_row[128];
  __shared__ float w3s[128];
  __shared__ float red[256];
  __shared__ float red2[4];

  const int tid = threadIdx.x;
  const int b = blockIdx.x >> 7, i = blockIdx.x & 127;
  const float* vpb = vp + ((size_t)b << 14);
  const float* vpi = vpb + (i << 7);
  const size_t rowoff = ((size_t)blockIdx.x) << 7;

  const int wv = tid >> 6;
  const int ln = tid & 63;
  const int qd = ln >> 4;
  const int cc = ln & 15;

  {
    const int j = tid >> 1;
    const int c0 = (tid & 1) << 6;
    const int m = j >> 4, ccr = j & 15;
    const float* vpj = vpb + (j << 7) + c0;
    const float* vpx = vpi + c0;
#pragma unroll
    for (int c = 0; c < 64; c += 8) {
      const int gc = c0 + c;
      const int kt = gc >> 5, qdw = (gc >> 3) & 3;
      float4 a0 = *(const float4*)(vpj + c);
      float4 a1 = *(const float4*)(vpj + c + 4);
      float4 b0 = *(const float4*)(vpx + c);
      float4 b1 = *(const float4*)(vpx + c + 4);
      bf16x8 t;
      float d;
      d = a0.x - b0.x; t[0] = (__bf16)(d * d);
      d = a0.y - b0.y; t[1] = (__bf16)(d * d);
      d = a0.z - b0.z; t[2] = (__bf16)(d * d);
      d = a0.w - b0.w; t[3] = (__bf16)(d * d);
      d = a1.x - b1.x; t[4] = (__bf16)(d * d);
      d = a1.y - b1.y; t[5] = (__bf16)(d * d);
      d = a1.z - b1.z; t[6] = (__bf16)(d * d);
      d = a1.w - b1.w; t[7] = (__bf16)(d * d);
      *(bf16x8*)&simf[(((kt << 3) + m) << 6 | (qdw << 4 | ccr)) << 3] = t;
    }
    if (tid < 128) {
      ep_row[tid] = (tid == i) ? 0.f : ep_in[rowoff + tid];
      w3s[tid] = w3[tid];
    }
  }

  bf16x8 bw[4], bw2[2][2];
#pragma unroll
  for (int kt = 0; kt < 4; kt++)
    bw[kt] = *(const bf16x8*)&w1b[(((0 * 4 + kt) * 4 + wv) * 64 + ln) * 8];
#pragma unroll
  for (int nt = 0; nt < 2; nt++)
#pragma unroll
    for (int kt = 0; kt < 2; kt++)
      bw2[nt][kt] = *(const bf16x8*)&w2b[((((0 * 2 + nt) * 2 + kt) * 4 + wv) * 64 + ln) * 8];

  __syncthreads();

  floatx4 acc2[8][2];
#pragma unroll
  for (int m = 0; m < 8; m++) {
    acc2[m][0] = (floatx4){0.f, 0.f, 0.f, 0.f};
    acc2[m][1] = (floatx4){0.f, 0.f, 0.f, 0.f};
  }

  const int h1h = wv >> 1;
  const int h1qd = ((wv & 1) << 1) | (cc >> 3);
  const int h1jj = cc & 7;

#pragma unroll
  for (int qtr = 0; qtr < 4; qtr++) {
    bf16x8 bwn[4], bw2n[2][2];
    if (qtr < 3) {
#pragma unroll
      for (int kt = 0; kt < 4; kt++)
        bwn[kt] = *(const bf16x8*)&w1b[((((qtr + 1) * 4 + kt) * 4 + wv) * 64 + ln) * 8];
#pragma unroll
      for (int nt = 0; nt < 2; nt++)
#pragma unroll
        for (int kt = 0; kt < 2; kt++)
          bw2n[nt][kt] = *(const bf16x8*)&w2b[(((((qtr + 1) * 2 + nt) * 2 + kt) * 4 + wv) * 64 + ln) * 8];
    }

#pragma unroll
    for (int m2 = 0; m2 < 8; m2 += 2) {
      bf16x8 af0[4], af1[4];
#pragma unroll
      for (int kt = 0; kt < 4; kt++) {
        af0[kt] = *(const bf16x8*)&simf[(((kt << 3) + m2) << 6 | ln) << 3];
        af1[kt] = *(const bf16x8*)&simf[(((kt << 3) + m2 + 1) << 6 | ln) << 3];
      }
      floatx4 x0 = (floatx4){0.f, 0.f, 0.f, 0.f};
      floatx4 x1 = (floatx4){0.f, 0.f, 0.f, 0.f};
#pragma unroll
      for (int kt = 0; kt < 4; kt++) {
        x0 = MFMA(af0[kt], bw[kt], x0);
        x1 = MFMA(af1[kt], bw[kt], x1);
      }
#pragma unroll
      for (int r = 0; r < 4; r++) {
        float v0 = x0[r] * BNS;
        float v1 = x1[r] * BNS;
        hbf[(((h1h * 8 + m2) * 64) + h1qd * 16 + qd * 4 + r) * 8 + h1jj] = (__bf16)LRELU(v0);
        hbf[(((h1h * 8 + m2 + 1) * 64) + h1qd * 16 + qd * 4 + r) * 8 + h1jj] = (__bf16)LRELU(v1);
      }
    }
    __syncthreads();

#pragma unroll
    for (int m = 0; m < 8; m++) {
      bf16x8 a0 = *(const bf16x8*)&hbf[((m << 6) | ln) << 3];
      bf16x8 a1 = *(const bf16x8*)&hbf[(((8 + m) << 6) | ln) << 3];
      acc2[m][0] = MFMA(a0, bw2[0][0], acc2[m][0]);
      acc2[m][1] = MFMA(a0, bw2[1][0], acc2[m][1]);
      acc2[m][0] = MFMA(a1, bw2[0][1], acc2[m][0]);
      acc2[m][1] = MFMA(a1, bw2[1][1], acc2[m][1]);
    }
    __syncthreads();

    if (qtr < 3) {
#pragma unroll
      for (int kt = 0; kt < 4; kt++) bw[kt] = bwn[kt];
#pragma unroll
      for (int nt = 0; nt < 2; nt++)
#pragma unroll
        for (int kt = 0; kt < 2; kt++) bw2[nt][kt] = bw2n[nt][kt];
    }
  }

  {
    const int seg = wv;
#pragma unroll
    for (int m = 0; m < 8; m++)
#pragma unroll
      for (int nt = 0; nt < 2; nt++) {
        const int q2 = (nt << 1) | (cc >> 3);
#pragma unroll
        for (int r = 0; r < 4; r++) {
          float v = acc2[m][nt][r] * BNS;
          simf[(((seg * 8 + m) * 64) + q2 * 16 + qd * 4 + r) * 8 + (cc & 7)] = (__bf16)LRELU(v);
        }
      }
  }
  __syncthreads();

  {
    const int j = tid & 127, hh = tid >> 7;
    const int m = j >> 4, R = j & 15;
    float s = 0.f;
#pragma unroll
    for (int sg = 0; sg < 2; sg++) {
      const int seg = hh * 2 + sg;
#pragma unroll
      for (int q3 = 0; q3 < 4; q3++) {
        bf16x8 f = *(const bf16x8*)&simf[(((seg * 8 + m) * 64) + q3 * 16 + R) * 8];
        const float* wp = &w3s[seg * 32 + q3 * 8];
#pragma unroll
        for (int jj = 0; jj < 8; jj++) s += (float)f[jj] * wp[jj];
      }
    }
    red[tid] = s;
  }
  __syncthreads();
  if (tid < 128) {
    float s = red[tid] + red[tid + 128] + b3[0];
    float sg = 1.f / (1.f + expf(-s));
    e_row[tid] = sg * ep_row[tid];
  }
  __syncthreads();

  {
    float v = (tid < 128) ? ep_row[tid] : 0.f;
    float w = wave_sum(v);
    if (ln == 0) red2[wv] = w;
  }
  __syncthreads();
  const float ep_sum = red2[0] + red2[1];

  if (kval > 0) {
    const int j = tid & 127, hh = tid >> 7;
    const float v = e_row[j];
    int cnt = 0;
    const int base = hh << 6;
#pragma unroll 8
    for (int jj = 0; jj < 64; jj++) {
      float u = e_row[base + jj];
      cnt += (u > v || (u == v && (base + jj) < j)) ? 1 : 0;
    }
    red[tid] = (float)cnt;
  }
  __syncthreads();

  float em = 0.f;
  if (tid < 128) {
    float v = e_row[tid];
    if (kval > 0) {
      int cnt = (int)red[tid] + (int)red[tid + 128];
      em = (cnt < kval) ? v : 0.f;
    } else {
      em = v;
    }
  }
  {
    float w = wave_sum((tid < 128) ? em : 0.f);
    if (ln == 0) red2[wv] = w;
  }
  __syncthreads();
  const float l1 = red2[0] + red2[1];
  __syncthreads();

  const float scale = ep_sum / fmaxf(l1, 1e-12f);
  float val = 0.f;
  if (tid < 128) val = em * scale + ((tid == i) ? 1.f : 0.f) + 1e-6f;
  {
    float w = wave_sum((tid < 128) ? val : 0.f);
    if (ln == 0) red2[wv] = w;
  }
  __syncthreads();
  const float rsum = red2[0] + red2[1];

  if (tid < 128) {
    float o = val / rsum;
    ep_out[rowoff + tid] = o;
    if (outp) outp[rowoff + tid] = o;
  }
}

// ---------------------------------------------------------------------------
// k_qk (gen-1 only): interleaved bf16x8 weights, 16 coalesced 16B loads/thread.
// ---------------------------------------------------------------------------
__global__ __launch_bounds__(256) void k_qk(const float* __restrict__ vp,
                                            const __bf16* __restrict__ qkw,
                                            float* __restrict__ qo,
                                            float* __restrict__ ko) {
  __shared__ float vr[128];
  const int t = threadIdx.x;
  const size_t rowoff = ((size_t)blockIdx.x) << 7;
  if (t < 128) vr[t] = vp[rowoff + t];
  __syncthreads();
  const int o = t & 127;
  const __bf16* base = qkw + ((t >> 7) ? 16384 : 0);
  const float4* vr4 = (const float4*)vr;
  float a = 0.f;
#pragma unroll
  for (int cb = 0; cb < 16; cb++) {
    bf16x8 w8 = *(const bf16x8*)&base[(cb * 128 + o) * 8];
    float4 v0 = vr4[2 * cb], v1 = vr4[2 * cb + 1];
    a += v0.x * (float)w8[0] + v0.y * (float)w8[1] + v0.z * (float)w8[2] + v0.w * (float)w8[3] +
         v1.x * (float)w8[4] + v1.y * (float)w8[5] + v1.z * (float)w8[6] + v1.w * (float)w8[7];
  }
  float* dst = (t < 128) ? qo : ko;
  dst[rowoff + o] = a;
}

// ---------------------------------------------------------------------------
// k_attn_agg: 2-row attn/edge/aggr (grid 512); writes agg to global. (r9)
// ---------------------------------------------------------------------------
__global__ __launch_bounds__(256) void k_attn_agg(const float* __restrict__ qv,
                                                  const float* __restrict__ kv,
                                                  const float* __restrict__ ep,
                                                  const float* __restrict__ vp_in,
                                                  float* __restrict__ agg) {
  __shared__ float qi[256];
  __shared__ float sbuf[1024];
  __shared__ float er[256];
  __shared__ float pbuf[2048];
  __shared__ float red2[4];

  const int tid = threadIdx.x;
  const int wv = tid >> 6, ln = tid & 63;
  const int b = blockIdx.x >> 6;
  const int r0 = (blockIdx.x & 63) * 2;
  const size_t rowoff0 = ((size_t)(b * 128 + r0)) << 7;
  const float* vpbb = vp_in + ((size_t)b << 14);

  qi[tid] = qv[rowoff0 + tid];
  __syncthreads();

  {
    const int j = tid & 127, hh = tid >> 7;
    const float* krow = kv + (((size_t)(b * 128 + j)) << 7);
    const int h0 = hh * 2, h1 = hh * 2 + 1;
    float s00 = 0.f, s01 = 0.f, s10 = 0.f, s11 = 0.f;
#pragma unroll
    for (int d = 0; d < 32; d += 4) {
      float4 k0 = *(const float4*)(krow + h0 * 32 + d);
      float4 k1 = *(const float4*)(krow + h1 * 32 + d);
      s00 += qi[h0 * 32 + d] * k0.x + qi[h0 * 32 + d + 1] * k0.y +
             qi[h0 * 32 + d + 2] * k0.z + qi[h0 * 32 + d + 3] * k0.w;
      s01 += qi[h1 * 32 + d] * k1.x + qi[h1 * 32 + d + 1] * k1.y +
             qi[h1 * 32 + d + 2] * k1.z + qi[h1 * 32 + d + 3] * k1.w;
      s10 += qi[128 + h0 * 32 + d] * k0.x + qi[128 + h0 * 32 + d + 1] * k0.y +
             qi[128 + h0 * 32 + d + 2] * k0.z + qi[128 + h0 * 32 + d + 3] * k0.w;
      s11 += qi[128 + h1 * 32 + d] * k1.x + qi[128 + h1 * 32 + d + 1] * k1.y +
             qi[128 + h1 * 32 + d + 2] * k1.z + qi[128 + h1 * 32 + d + 3] * k1.w;
    }
    const float sc = 0.17677669529663687f;
    sbuf[(0 * 4 + h0) * 128 + j] = s00 * sc;
    sbuf[(0 * 4 + h1) * 128 + j] = s01 * sc;
    sbuf[(1 * 4 + h0) * 128 + j] = s10 * sc;
    sbuf[(1 * 4 + h1) * 128 + j] = s11 * sc;
  }
  __syncthreads();

  {
    const int g = wv;
#pragma unroll
    for (int row = 0; row < 2; row++) {
      float a = sbuf[(row * 4 + g) * 128 + ln];
      float bb = sbuf[(row * 4 + g) * 128 + 64 + ln];
      float mx = wave_max(fmaxf(a, bb));
      float e0 = expf(a - mx), e1 = expf(bb - mx);
      float Z = wave_sum(e0 + e1);
      sbuf[(row * 4 + g) * 128 + ln] = e0 / Z;
      sbuf[(row * 4 + g) * 128 + 64 + ln] = e1 / Z;
    }
  }
  __syncthreads();

  {
    const int row = tid >> 7, j = tid & 127;
    float attn = 0.25f * (sbuf[(row * 4) * 128 + j] + sbuf[(row * 4 + 1) * 128 + j] +
                          sbuf[(row * 4 + 2) * 128 + j] + sbuf[(row * 4 + 3) * 128 + j]);
    float eraw = (j == r0 + row) ? 0.f : ep[rowoff0 + tid] * attn;
    float w = wave_sum(eraw);
    if (ln == 0) red2[wv] = w;
    __syncthreads();
    float l1row = red2[row * 2] + red2[row * 2 + 1];
    er[tid] = eraw / fmaxf(l1row, 1e-12f);
  }
  __syncthreads();

  {
    const int cg = tid & 31, jg = tid >> 5;
    float4 a0 = {0.f, 0.f, 0.f, 0.f}, a1 = {0.f, 0.f, 0.f, 0.f};
#pragma unroll
    for (int jj = 0; jj < 16; jj++) {
      const int j = jg * 16 + jj;
      float4 v = *(const float4*)(vpbb + (j << 7) + (cg << 2));
      float e0 = er[j], e1 = er[128 + j];
      a0.x += e0 * v.x; a0.y += e0 * v.y; a0.z += e0 * v.z; a0.w += e0 * v.w;
      a1.x += e1 * v.x; a1.y += e1 * v.y; a1.z += e1 * v.z; a1.w += e1 * v.w;
    }
    *(float4*)&pbuf[(jg * 32 + cg) * 4] = a0;
    *(float4*)&pbuf[1024 + (jg * 32 + cg) * 4] = a1;
  }
  __syncthreads();
  {
    const int row = tid >> 7, c = tid & 127;
    float s = 0.f;
#pragma unroll
    for (int jg = 0; jg < 8; jg++) s += pbuf[(row << 10) + jg * 128 + c];
    agg[rowoff0 + tid] = s;
  }
}

// ---------------------------------------------------------------------------
// k_mlp: batched d2p MLP over all 1024 rows via MFMA (grid 64, unchanged).
// ---------------------------------------------------------------------------
__global__ __launch_bounds__(256) void k_mlp(const float* __restrict__ vp_in,
                                             const float* __restrict__ agg,
                                             const __bf16* __restrict__ d1,
                                             const __bf16* __restrict__ d2,
                                             float* __restrict__ vp_out) {
  __shared__ __bf16 hls[4096];
  const int tid = threadIdx.x;
  const int wv = tid >> 6, ln = tid & 63, qd = ln >> 4, cc = ln & 15;
  const int row = (blockIdx.x << 4) + cc;

  bf16x8 af[8];
#pragma unroll
  for (int kt = 0; kt < 4; kt++) {
    const float* p = vp_in + (size_t)row * 128 + kt * 32 + qd * 8;
    float4 v0 = *(const float4*)p, v1 = *(const float4*)(p + 4);
    bf16x8 t;
    t[0] = (__bf16)v0.x; t[1] = (__bf16)v0.y; t[2] = (__bf16)v0.z; t[3] = (__bf16)v0.w;
    t[4] = (__bf16)v1.x; t[5] = (__bf16)v1.y; t[6] = (__bf16)v1.z; t[7] = (__bf16)v1.w;
    af[kt] = t;
  }
#pragma unroll
  for (int kt = 0; kt < 4; kt++) {
    const float* p = agg + (size_t)row * 128 + kt * 32 + qd * 8;
    float4 v0 = *(const float4*)p, v1 = *(const float4*)(p + 4);
    bf16x8 t;
    t[0] = (__bf16)v0.x; t[1] = (__bf16)v0.y; t[2] = (__bf16)v0.z; t[3] = (__bf16)v0.w;
    t[4] = (__bf16)v1.x; t[5] = (__bf16)v1.y; t[6] = (__bf16)v1.z; t[7] = (__bf16)v1.w;
    af[4 + kt] = t;
  }

#pragma unroll
  for (int nt = 0; nt < 4; nt++) {
    const int ntg = wv * 4 + nt;
    floatx4 acc = (floatx4){0.f, 0.f, 0.f, 0.f};
#pragma unroll
    for (int kt = 0; kt < 8; kt++) {
      bf16x8 bw = *(const bf16x8*)&d1[((size_t)(ntg * 8 + kt) * 64 + ln) * 8];
      acc = MFMA(af[kt], bw, acc);
    }
    const int col = ntg * 16 + cc;
    const int kt2 = col >> 5, qd2 = (col >> 3) & 3, jjs = col & 7;
#pragma unroll
    for (int r = 0; r < 4; r++) {
      float h = acc[r] * BNS;
      const int m = qd * 4 + r;
      hls[((kt2 * 64) + qd2 * 16 + m) * 8 + jjs] = (__bf16)LRELU(h);
    }
  }
  __syncthreads();

  bf16x8 a2[8];
#pragma unroll
  for (int kt2 = 0; kt2 < 8; kt2++)
    a2[kt2] = *(const bf16x8*)&hls[(kt2 * 64 + ln) * 8];
#pragma unroll
  for (int nt = 0; nt < 2; nt++) {
    const int ntg = wv * 2 + nt;
    floatx4 o = (floatx4){0.f, 0.f, 0.f, 0.f};
#pragma unroll
    for (int kt2 = 0; kt2 < 8; kt2++) {
      bf16x8 bw = *(const bf16x8*)&d2[((size_t)(ntg * 8 + kt2) * 64 + ln) * 8];
      o = MFMA(a2[kt2], bw, o);
    }
    const int col = ntg * 16 + cc;
#pragma unroll
    for (int r = 0; r < 4; r++) {
      float v = o[r] * BNS;
      const int m = qd * 4 + r;
      vp_out[(size_t)((blockIdx.x << 4) + m) * 128 + col] = LRELU(v);
    }
  }
}

// ---------------------------------------------------------------------------
extern "C" void kernel_launch(void* const* d_in, const int* in_sizes, int n_in,
                              void* d_out, int out_size, void* d_ws, size_t ws_size,
                              hipStream_t stream) {
  const float* vp0    = (const float*)d_in[0];
  const float* ep0    = (const float*)d_in[1];
  const float* pre_w1 = (const float*)d_in[2];
  const float* pre_w2 = (const float*)d_in[3];
  const float* pre_w3 = (const float*)d_in[4];
  const float* pre_b3 = (const float*)d_in[5];
  const float* ps_w1  = (const float*)d_in[6];
  const float* ps_w2  = (const float*)d_in[7];
  const float* ps_w3  = (const float*)d_in[8];
  const float* ps_b3  = (const float*)d_in[9];
  const float* dw1    = (const float*)d_in[10];
  const float* dw2    = (const float*)d_in[11];
  const float* mwq    = (const float*)d_in[12];
  const float* mwk    = (const float*)d_in[13];

  char* ws = (char*)d_ws;
  float* ep   = (float*)(ws);                      // 512 KB
  float* vpb  = (float*)(ws + (512ull << 10));     // 512 KB
  float* vpa  = (float*)(ws + (1024ull << 10));    // 512 KB
  float* qf   = (float*)(ws + (1536ull << 10));    // 512 KB
  float* kf   = (float*)(ws + (2048ull << 10));    // 512 KB
  __bf16* w1b = (__bf16*)(ws + (2560ull << 10));            // 192 KB
  __bf16* w2b = (__bf16*)(ws + (2560ull << 10) + 196608);   // 192 KB
  __bf16* d1i = (__bf16*)(ws + (2560ull << 10) + 393216);   // 256 KB
  __bf16* d2i = (__bf16*)(ws + (2560ull << 10) + 655360);   // 128 KB
  __bf16* qki = (__bf16*)(ws + (2560ull << 10) + 786432);   // 128 KB
  float* agg  = (float*)(ws + (2560ull << 10) + 917504);    // 512 KB
  float* outp = (float*)d_out;

  // prep swizzles + gen-0 q/k projection in one launch (independent work)
  k_prep<<<1248, 256, 0, stream>>>(pre_w1, ps_w1, pre_w2, ps_w2, dw1, dw2, mwq, mwk,
                                   vp0, w1b, w2b, d1i, d2i, qki, qf, kf);

  // pre-psim (no top-k)
  k_psim<<<1024, 256, 0, stream>>>(vp0, ep0, ep, w1b, w2b, pre_w3, pre_b3, 0, nullptr);

  // generation 0 (kval = 115) — qf/kf already produced by k_prep
  k_attn_agg<<<512, 256, 0, stream>>>(qf, kf, ep, vp0, agg);
  k_mlp<<<64, 256, 0, stream>>>(vp0, agg, d1i, d2i, vpb);
  k_psim<<<1024, 256, 0, stream>>>(vpb, ep, ep, w1b + 32768, w2b + 32768,
                                   ps_w3, ps_b3, 115, nullptr);

  // generation 1 (kval = 102)
  k_qk<<<1024, 256, 0, stream>>>(vpb, qki + 32768, qf, kf);
  k_attn_agg<<<512, 256, 0, stream>>>(qf, kf, ep, vpb, agg);
  k_mlp<<<64, 256, 0, stream>>>(vpb, agg, d1i + 65536, d2i + 32768, vpa);
  k_psim<<<1024, 256, 0, stream>>>(vpa, ep, ep, w1b + 65536, w2b + 65536,
                                   ps_w3 + 128, ps_b3 + 1, 102, outp);
}